// Round 1
// baseline (317.892 us; speedup 1.0000x reference)
//
#include <hip/hip_runtime.h>

// CARAFE on MI355X. Shapes: B=4, C=256, H=W=64, CMID=64, NK=100 (=s^2*k^2, s=2, k=5).
// Pipeline: k0 weight-transform -> k1 conv3x3+relu (NHWC feat) -> k2 conv1x1+softmax
// -> k3 reassembly + pixel-shuffle.
// Pixel-shuffle mapping (verified against reference reshape/transpose chain):
//   out[b, s*64 + c/4, 2h + (c%4)/2, 2w + (c%4)%2] = sum_k kern[b, s*25+k, h, w] * xpad[b, c, h+kh-2, w+kw-2]

#define BB 4
#define CC 256
#define HH 64
#define WW 64
#define CMID 64
#define NKCH 100

// workspace layout (floats)
#define FEAT_OFF 0
#define FEAT_ELEMS (BB*HH*WW*CMID)            // 1048576
#define KERN_OFF FEAT_ELEMS
#define KERN_ELEMS (BB*HH*WW*NKCH)            // 1638400
#define W1T_OFF (FEAT_ELEMS + KERN_ELEMS)
#define W1T_ELEMS (CC*9*CMID)                 // 147456

// ---------------- k0: w1 [oc][ic][3][3] -> w1t [ic][kk][oc] ----------------
__global__ void k0_transform(const float* __restrict__ w1, float* __restrict__ w1t) {
    int idx = blockIdx.x * 256 + threadIdx.x;
    if (idx >= W1T_ELEMS) return;
    int oc = idx & 63;
    int kk = (idx >> 6) % 9;
    int ic = idx / (9 * 64);
    w1t[idx] = w1[oc * (CC * 9) + ic * 9 + kk];
}

// ---------------- k1: conv3x3 (256->64) + relu, out feat NHWC ----------------
// grid = B*H blocks, 256 threads. Thread owns 4 oc x 4 w.
__global__ __launch_bounds__(256) void k1_conv3x3(const float* __restrict__ x,
        const float* __restrict__ w1t, const float* __restrict__ b1,
        float* __restrict__ feat) {
    int bh = blockIdx.x;
    int b = bh >> 6, h = bh & 63;
    int tid = threadIdx.x;
    int og = tid >> 4;           // 0..15 -> oc0 = og*4
    int wg = tid & 15;           // 0..15 -> w0 = wg*4
    int oc0 = og * 4, w0 = wg * 4;

    __shared__ float xs[16 * 3 * 68];   // [icc][r][col], data at col=w+2, pads zeroed
    __shared__ float ws[16 * 9 * 64];   // [icc][kk][oc]

    float acc[4][4];                     // [oc][w]
    #pragma unroll
    for (int o = 0; o < 4; ++o)
        #pragma unroll
        for (int j = 0; j < 4; ++j) acc[o][j] = 0.f;

    const float* xb = x + (size_t)b * CC * HH * WW;

    for (int ic0 = 0; ic0 < CC; ic0 += 16) {
        __syncthreads();  // guard WAR on LDS from previous iter
        // stage x rows h-1..h+1 for 16 input channels
        for (int i = tid; i < 16 * 3 * 64; i += 256) {
            int icc = i / 192;
            int r = (i / 64) % 3;
            int w = i & 63;
            int hr = h - 1 + r;
            float v = (hr >= 0 && hr < HH) ? xb[(ic0 + icc) * (HH * WW) + hr * WW + w] : 0.f;
            xs[(icc * 3 + r) * 68 + 2 + w] = v;
        }
        // zero pad columns 0,1,66,67
        for (int i = tid; i < 16 * 3 * 4; i += 256) {
            int icc = i / 12; int r = (i / 4) % 3; int p = i & 3;
            int col = (p < 2) ? p : (64 + p);
            xs[(icc * 3 + r) * 68 + col] = 0.f;
        }
        // stage weights (fully coalesced thanks to k0 transform)
        for (int i = tid; i < 16 * 9 * 64; i += 256) {
            ws[i] = w1t[ic0 * (9 * 64) + i];
        }
        __syncthreads();

        #pragma unroll 4
        for (int icc = 0; icc < 16; ++icc) {
            #pragma unroll
            for (int r = 0; r < 3; ++r) {
                const float* xrow = &xs[(icc * 3 + r) * 68];
                float4 a0 = *(const float4*)(xrow + w0);
                float4 a1 = *(const float4*)(xrow + w0 + 4);
                float xr[8] = {a0.x, a0.y, a0.z, a0.w, a1.x, a1.y, a1.z, a1.w};
                #pragma unroll
                for (int kw = 0; kw < 3; ++kw) {
                    float4 wv = *(const float4*)&ws[(icc * 9 + r * 3 + kw) * 64 + oc0];
                    float wf[4] = {wv.x, wv.y, wv.z, wv.w};
                    #pragma unroll
                    for (int j = 0; j < 4; ++j) {
                        float xv = xr[j + kw + 1];   // LDS col (w0+j)+(kw-1)+2
                        acc[0][j] += xv * wf[0];
                        acc[1][j] += xv * wf[1];
                        acc[2][j] += xv * wf[2];
                        acc[3][j] += xv * wf[3];
                    }
                }
            }
        }
    }

    float bb0 = b1[oc0 + 0], bb1 = b1[oc0 + 1], bb2 = b1[oc0 + 2], bb3 = b1[oc0 + 3];
    #pragma unroll
    for (int j = 0; j < 4; ++j) {
        int w = w0 + j;
        float4 o;
        o.x = fmaxf(acc[0][j] + bb0, 0.f);
        o.y = fmaxf(acc[1][j] + bb1, 0.f);
        o.z = fmaxf(acc[2][j] + bb2, 0.f);
        o.w = fmaxf(acc[3][j] + bb3, 0.f);
        *(float4*)&feat[((size_t)bh * 64 + w) * 64 + oc0] = o;   // NHWC
    }
}

// ---------------- k2: conv1x1 (64->100) + softmax over 100 -> kern [b][h][w][100] ----------------
// grid = B*H blocks, 256 threads. Thread = (w = tid&63, ocq = tid>>6 owns 25 oc).
__global__ __launch_bounds__(256) void k2_kernelpred(const float* __restrict__ feat,
        const float* __restrict__ w2, const float* __restrict__ b2,
        float* __restrict__ kern) {
    int bh = blockIdx.x;
    int tid = threadIdx.x;
    int w = tid & 63;
    int ocq = tid >> 6;

    __shared__ float fs[64 * 65];       // [ic][w], pad 65
    __shared__ float ws2[NKCH * 64];    // [oc][ic]
    __shared__ float red[2][4][64];

    for (int i = tid; i < 64 * 64; i += 256) {
        int ic = i & 63;                 // global feat NHWC: i = w*64 + ic
        int ww = i >> 6;
        fs[ic * 65 + ww] = feat[(size_t)bh * 4096 + i];
    }
    for (int i = tid; i < NKCH * 64; i += 256) ws2[i] = w2[i];
    __syncthreads();

    float fv[64];
    #pragma unroll
    for (int ic = 0; ic < 64; ++ic) fv[ic] = fs[ic * 65 + w];

    float lg[25];
    for (int i = 0; i < 25; ++i) {
        int oc = ocq * 25 + i;
        float a = b2[oc];
        const float* wr = &ws2[oc * 64];
        #pragma unroll
        for (int ic = 0; ic < 64; ++ic) a += fv[ic] * wr[ic];
        lg[i] = a;
    }

    // softmax over all 100 channels (4 thread partials per pixel)
    float m = -1e30f;
    #pragma unroll
    for (int i = 0; i < 25; ++i) m = fmaxf(m, lg[i]);
    red[0][ocq][w] = m;
    __syncthreads();
    m = fmaxf(fmaxf(red[0][0][w], red[0][1][w]), fmaxf(red[0][2][w], red[0][3][w]));
    float s = 0.f;
    #pragma unroll
    for (int i = 0; i < 25; ++i) { lg[i] = __expf(lg[i] - m); s += lg[i]; }
    red[1][ocq][w] = s;
    __syncthreads();
    s = red[1][0][w] + red[1][1][w] + red[1][2][w] + red[1][3][w];
    float inv = 1.f / s;
    float* kp = &kern[(size_t)bh * 6400 + w * 100 + ocq * 25];
    #pragma unroll
    for (int i = 0; i < 25; ++i) kp[i] = lg[i] * inv;
}

// ---------------- k3: reassembly + pixel shuffle ----------------
// grid = (16 c-chunks, B*H), 256 threads: w = tid&63, cg = tid>>6; c = chunk*16 + cg*4 + ci
__global__ __launch_bounds__(256) void k3_reassemble(const float* __restrict__ x,
        const float* __restrict__ kern, float* __restrict__ out) {
    int chunk = blockIdx.x;
    int bh = blockIdx.y;
    int b = bh >> 6, h = bh & 63;
    int tid = threadIdx.x;
    int w = tid & 63;
    int cg = tid >> 6;
    int cq = chunk * 4 + cg;     // c-quad 0..63 ; c = cq*4 + ci
    int cbase = chunk * 16;

    __shared__ float kt[NKCH * 66];     // [ch][w], pad 66
    __shared__ float xs[16 * 5 * 68];   // [cc][r][col], data at col=w+2

    for (int i = tid; i < 6400; i += 256) {
        int ww = i / 100, ch = i % 100;
        kt[ch * 66 + ww] = kern[(size_t)bh * 6400 + i];
    }
    for (int i = tid; i < 16 * 5 * 64; i += 256) {
        int cc = i / 320;
        int r = (i / 64) % 5;
        int ww = i & 63;
        int hr = h - 2 + r;
        float v = (hr >= 0 && hr < HH)
            ? x[(((size_t)b * CC + cbase + cc) * HH + hr) * WW + ww] : 0.f;
        xs[(cc * 5 + r) * 68 + 2 + ww] = v;
    }
    for (int i = tid; i < 16 * 5 * 4; i += 256) {
        int cc = i / 20; int r = (i / 4) % 5; int p = i & 3;
        int col = (p < 2) ? p : (64 + p);
        xs[(cc * 5 + r) * 68 + col] = 0.f;
    }
    __syncthreads();

    float acc[4][4];   // [s][ci]
    #pragma unroll
    for (int s = 0; s < 4; ++s)
        #pragma unroll
        for (int ci = 0; ci < 4; ++ci) acc[s][ci] = 0.f;

    int cloc = cg * 4;
    #pragma unroll
    for (int r = 0; r < 5; ++r) {
        #pragma unroll
        for (int kw = 0; kw < 5; ++kw) {
            int k = r * 5 + kw;
            float kv0 = kt[(0 * 25 + k) * 66 + w];
            float kv1 = kt[(1 * 25 + k) * 66 + w];
            float kv2 = kt[(2 * 25 + k) * 66 + w];
            float kv3 = kt[(3 * 25 + k) * 66 + w];
            #pragma unroll
            for (int ci = 0; ci < 4; ++ci) {
                float xv = xs[((cloc + ci) * 5 + r) * 68 + w + kw];
                acc[0][ci] += kv0 * xv;
                acc[1][ci] += kv1 * xv;
                acc[2][ci] += kv2 * xv;
                acc[3][ci] += kv3 * xv;
            }
        }
    }

    // out[b, s*64+cq, 2h+s1, 2w+s2], ci = s1*2+s2 -> coalesced float2 along x
    #pragma unroll
    for (int s = 0; s < 4; ++s) {
        int co = s * 64 + cq;
        #pragma unroll
        for (int s1 = 0; s1 < 2; ++s1) {
            float2 v = make_float2(acc[s][s1 * 2 + 0], acc[s][s1 * 2 + 1]);
            *(float2*)&out[(((size_t)b * 256 + co) * 128 + 2 * h + s1) * 128 + 2 * w] = v;
        }
    }
}

extern "C" void kernel_launch(void* const* d_in, const int* in_sizes, int n_in,
                              void* d_out, int out_size, void* d_ws, size_t ws_size,
                              hipStream_t stream) {
    const float* x  = (const float*)d_in[0];
    const float* w1 = (const float*)d_in[1];
    const float* b1 = (const float*)d_in[2];
    const float* w2 = (const float*)d_in[3];
    const float* b2 = (const float*)d_in[4];
    float* out = (float*)d_out;

    float* wsf  = (float*)d_ws;
    float* feat = wsf + FEAT_OFF;
    float* kern = wsf + KERN_OFF;
    float* w1t  = wsf + W1T_OFF;

    k0_transform<<<dim3((W1T_ELEMS + 255) / 256), 256, 0, stream>>>(w1, w1t);
    k1_conv3x3<<<dim3(BB * HH), 256, 0, stream>>>(x, w1t, b1, feat);
    k2_kernelpred<<<dim3(BB * HH), 256, 0, stream>>>(feat, w2, b2, kern);
    k3_reassemble<<<dim3(16, BB * HH), 256, 0, stream>>>(x, kern, out);
}

// Round 2
// 182.502 us; speedup vs baseline: 1.7419x; 1.7419x over previous
//
#include <hip/hip_runtime.h>

// CARAFE on MI355X. B=4, C=256, H=W=64, CMID=64, NK=100 (s=2, k=5).
// k0a: w1 -> w1b bf16 [kk][oc][ic]
// k1 : conv3x3+relu as bf16 MFMA implicit GEMM (9 shifted K=256 GEMMs), feat bf16 NHWC
// k2 : conv1x1 (64->100) + softmax -> kern fp32 [bh][w][100]
// k3 : reassembly + pixel shuffle (fp32)
// out[b, s*64 + c/4, 2h + (c%4)/2, 2w + (c%4)%2] = sum_k kern[b,s*25+k,h,w] * xpad[b,c,h+kh-2,w+kw-2]

#define BB 4
#define CC 256
#define HH 64
#define WW 64
#define CMID 64
#define NKCH 100

typedef __bf16 bf16;
typedef __bf16 bf16x8 __attribute__((ext_vector_type(8)));
typedef float f32x4 __attribute__((ext_vector_type(4)));

// workspace layout (bytes)
// featb: 1048576 bf16  @ 0         (2,097,152 B)
// kern : 1638400 f32   @ 2097152   (6,553,600 B)
// w1b  : 147456  bf16  @ 8650752   (294,912 B)
#define FEAT_ELEMS (BB*HH*WW*CMID)
#define KERN_ELEMS (BB*HH*WW*NKCH)
#define W1B_ELEMS (9*CMID*CC)

__device__ __forceinline__ void async_copy16(const void* gsrc, void* ldst) {
    __builtin_amdgcn_global_load_lds(
        (__attribute__((address_space(1))) void*)(void*)gsrc,
        (__attribute__((address_space(3))) void*)ldst, 16, 0, 0);
}

// ---------------- k0a: w1 [oc][ic][3][3] fp32 -> w1b [kk][oc][ic] bf16 ----------------
__global__ void k0a_transform(const float* __restrict__ w1, bf16* __restrict__ w1b) {
    int idx = blockIdx.x * 256 + threadIdx.x;
    if (idx >= W1B_ELEMS) return;
    int ic = idx & 255;
    int oc = (idx >> 8) & 63;
    int kk = idx >> 14;
    w1b[idx] = (bf16)w1[(oc * 256 + ic) * 9 + kk];
}

// ---------------- k1: conv3x3 (256->64) + relu via MFMA, feat bf16 NHWC ----------------
// grid = 256 blocks (bh), 256 threads = 4 waves. Wave (mhalf, nhalf): 32 oc x 32 px tile.
// GEMM: D[oc][px] = sum_{kk,ic} W[oc][kk,ic] * X[ic][px shifted by (kk)]
#define XS_STRIDE 40   // padded ic-slot stride (elements); 80 B = 20 banks, 16B-aligned
__global__ __launch_bounds__(256) void k1_mfma(const float* __restrict__ x,
        const bf16* __restrict__ w1b, const float* __restrict__ b1,
        bf16* __restrict__ featb) {
    int bh = blockIdx.x;
    int b = bh >> 6, h = bh & 63;
    int tid = threadIdx.x;
    int lane = tid & 63, wid = tid >> 6;
    int l15 = lane & 15, quad = lane >> 4;
    int mhalf = wid & 1, nhalf = wid >> 1;

    __shared__ __align__(16) bf16 xs[3 * 66 * XS_STRIDE];   // [row][colslot][icpad]
    __shared__ __align__(16) bf16 wlds[9 * 64 * 32];        // [kk][oc][ic32]

    // zero xs once: covers side pads (colslot 0,65) and OOB rows permanently
    for (int i = tid; i < 3 * 66 * XS_STRIDE; i += 256) xs[i] = (bf16)0.f;

    f32x4 acc00 = {0.f, 0.f, 0.f, 0.f}, acc01 = {0.f, 0.f, 0.f, 0.f};
    f32x4 acc10 = {0.f, 0.f, 0.f, 0.f}, acc11 = {0.f, 0.f, 0.f, 0.f};

    const float* xb = x + (size_t)b * (CC * HH * WW);
    int sw = tid >> 2, sq = tid & 3;    // staging: col, ic-pair phase

    for (int ic0 = 0; ic0 < 256; ic0 += 32) {
        __syncthreads();   // previous chunk's compute done -> LDS reusable
        // stage x rows h-1..h+1, ic window [ic0, ic0+32), packed bf16 pairs
        #pragma unroll
        for (int r = 0; r < 3; ++r) {
            int hr = h - 1 + r;
            if (hr >= 0 && hr < HH) {
                #pragma unroll
                for (int j = 0; j < 4; ++j) {
                    int p = sq + j * 4;          // ic-pair index 0..15
                    int ic = ic0 + 2 * p;
                    float f0 = xb[(size_t)ic * (HH * WW) + hr * WW + sw];
                    float f1 = xb[(size_t)(ic + 1) * (HH * WW) + hr * WW + sw];
                    union { bf16 hh[2]; unsigned u; } cv;
                    cv.hh[0] = (bf16)f0; cv.hh[1] = (bf16)f1;
                    *(unsigned*)&xs[(r * 66 + 1 + sw) * XS_STRIDE + 2 * p] = cv.u;
                }
            }
        }
        // async-stage weights: 36 tasks (kk, oc-chunk of 16); lds dst wave-uniform
        for (int t = wid; t < 36; t += 4) {
            int kk = t >> 2, o0 = (t & 3) * 16;
            const bf16* g = w1b + ((size_t)(kk * 64 + o0 + (lane >> 2)) * 256 + ic0 + (lane & 3) * 8);
            async_copy16(g, (void*)&wlds[(kk * 64 + o0) * 32]);
        }
        __syncthreads();   // drains lgkmcnt (ds_write) + vmcnt (global_load_lds)

        #pragma unroll
        for (int kk = 0; kk < 9; ++kk) {
            const int r = kk / 3, kw = kk % 3;
            bf16x8 a0 = *(const bf16x8*)&wlds[(kk * 64 + mhalf * 32 + l15) * 32 + quad * 8];
            bf16x8 a1 = *(const bf16x8*)&wlds[(kk * 64 + mhalf * 32 + 16 + l15) * 32 + quad * 8];
            bf16x8 b0 = *(const bf16x8*)&xs[(r * 66 + nhalf * 32 + l15 + kw) * XS_STRIDE + quad * 8];
            bf16x8 b1v = *(const bf16x8*)&xs[(r * 66 + nhalf * 32 + 16 + l15 + kw) * XS_STRIDE + quad * 8];
            acc00 = __builtin_amdgcn_mfma_f32_16x16x32_bf16(a0, b0, acc00, 0, 0, 0);
            acc01 = __builtin_amdgcn_mfma_f32_16x16x32_bf16(a0, b1v, acc01, 0, 0, 0);
            acc10 = __builtin_amdgcn_mfma_f32_16x16x32_bf16(a1, b0, acc10, 0, 0, 0);
            acc11 = __builtin_amdgcn_mfma_f32_16x16x32_bf16(a1, b1v, acc11, 0, 0, 0);
        }
    }

    // epilogue: bias + relu, store bf16 NHWC. D: col(lane&15)=px, row(quad*4+reg)=oc
    f32x4 accs[2][2] = {{acc00, acc01}, {acc10, acc11}};
    #pragma unroll
    for (int mi = 0; mi < 2; ++mi) {
        int oc0 = mhalf * 32 + mi * 16 + quad * 4;
        float4 bv = *(const float4*)&b1[oc0];
        #pragma unroll
        for (int ni = 0; ni < 2; ++ni) {
            int c = nhalf * 32 + ni * 16 + l15;
            f32x4 v = accs[mi][ni];
            union { bf16 hh[4]; uint2 u; } o;
            o.hh[0] = (bf16)fmaxf(v[0] + bv.x, 0.f);
            o.hh[1] = (bf16)fmaxf(v[1] + bv.y, 0.f);
            o.hh[2] = (bf16)fmaxf(v[2] + bv.z, 0.f);
            o.hh[3] = (bf16)fmaxf(v[3] + bv.w, 0.f);
            *(uint2*)&featb[((size_t)bh * 64 + c) * 64 + oc0] = o.u;
        }
    }
}

// ---------------- k2: conv1x1 (64->100) + softmax over 100 -> kern [b][h][w][100] ----------------
__global__ __launch_bounds__(256) void k2_kernelpred(const bf16* __restrict__ featb,
        const float* __restrict__ w2, const float* __restrict__ b2,
        float* __restrict__ kern) {
    int bh = blockIdx.x;
    int tid = threadIdx.x;
    int w = tid & 63;
    int ocq = tid >> 6;

    __shared__ float fs[64 * 65];       // [ic][w], pad 65
    __shared__ __align__(16) float ws2[NKCH * 64];    // [oc][ic]
    __shared__ float red[2][4][64];

    for (int i = tid; i < 64 * 64; i += 256) {
        int ic = i & 63;
        int ww = i >> 6;
        fs[ic * 65 + ww] = (float)featb[(size_t)bh * 4096 + i];
    }
    for (int i = tid; i < NKCH * 64; i += 256) ws2[i] = w2[i];
    __syncthreads();

    float4 fv[16];
    #pragma unroll
    for (int q = 0; q < 16; ++q) {
        fv[q].x = fs[(4 * q + 0) * 65 + w];
        fv[q].y = fs[(4 * q + 1) * 65 + w];
        fv[q].z = fs[(4 * q + 2) * 65 + w];
        fv[q].w = fs[(4 * q + 3) * 65 + w];
    }

    float lg[25];
    for (int i = 0; i < 25; ++i) {
        int oc = ocq * 25 + i;
        float a = b2[oc];
        const float4* wr = (const float4*)&ws2[oc * 64];   // wave-uniform -> LDS broadcast
        #pragma unroll
        for (int q = 0; q < 16; ++q) {
            float4 wv = wr[q];
            a += fv[q].x * wv.x + fv[q].y * wv.y + fv[q].z * wv.z + fv[q].w * wv.w;
        }
        lg[i] = a;
    }

    float m = -1e30f;
    #pragma unroll
    for (int i = 0; i < 25; ++i) m = fmaxf(m, lg[i]);
    red[0][ocq][w] = m;
    __syncthreads();
    m = fmaxf(fmaxf(red[0][0][w], red[0][1][w]), fmaxf(red[0][2][w], red[0][3][w]));
    float s = 0.f;
    #pragma unroll
    for (int i = 0; i < 25; ++i) { lg[i] = __expf(lg[i] - m); s += lg[i]; }
    red[1][ocq][w] = s;
    __syncthreads();
    s = red[1][0][w] + red[1][1][w] + red[1][2][w] + red[1][3][w];
    float inv = 1.f / s;
    float* kp = &kern[(size_t)bh * 6400 + w * 100 + ocq * 25];
    #pragma unroll
    for (int i = 0; i < 25; ++i) kp[i] = lg[i] * inv;
}

// ---------------- k3: reassembly + pixel shuffle ----------------
__global__ __launch_bounds__(256) void k3_reassemble(const float* __restrict__ x,
        const float* __restrict__ kern, float* __restrict__ out) {
    int chunk = blockIdx.x;
    int bh = blockIdx.y;
    int b = bh >> 6, h = bh & 63;
    int tid = threadIdx.x;
    int w = tid & 63;
    int cg = tid >> 6;
    int cq = chunk * 4 + cg;
    int cbase = chunk * 16;

    __shared__ float kt[NKCH * 66];     // [ch][w], pad 66
    __shared__ float xs[16 * 5 * 68];   // [cc][r][col], data at col=w+2

    for (int i = tid; i < 6400; i += 256) {
        int ww = i / 100, ch = i % 100;
        kt[ch * 66 + ww] = kern[(size_t)bh * 6400 + i];
    }
    for (int i = tid; i < 16 * 5 * 64; i += 256) {
        int cc = i / 320;
        int r = (i / 64) % 5;
        int ww = i & 63;
        int hr = h - 2 + r;
        float v = (hr >= 0 && hr < HH)
            ? x[(((size_t)b * CC + cbase + cc) * HH + hr) * WW + ww] : 0.f;
        xs[(cc * 5 + r) * 68 + 2 + ww] = v;
    }
    for (int i = tid; i < 16 * 5 * 4; i += 256) {
        int cc = i / 20; int r = (i / 4) % 5; int p = i & 3;
        int col = (p < 2) ? p : (64 + p);
        xs[(cc * 5 + r) * 68 + col] = 0.f;
    }
    __syncthreads();

    float acc[4][4];   // [s][ci]
    #pragma unroll
    for (int s = 0; s < 4; ++s)
        #pragma unroll
        for (int ci = 0; ci < 4; ++ci) acc[s][ci] = 0.f;

    int cloc = cg * 4;
    #pragma unroll
    for (int r = 0; r < 5; ++r) {
        #pragma unroll
        for (int kw = 0; kw < 5; ++kw) {
            int k = r * 5 + kw;
            float kv0 = kt[(0 * 25 + k) * 66 + w];
            float kv1 = kt[(1 * 25 + k) * 66 + w];
            float kv2 = kt[(2 * 25 + k) * 66 + w];
            float kv3 = kt[(3 * 25 + k) * 66 + w];
            #pragma unroll
            for (int ci = 0; ci < 4; ++ci) {
                float xv = xs[((cloc + ci) * 5 + r) * 68 + w + kw];
                acc[0][ci] += kv0 * xv;
                acc[1][ci] += kv1 * xv;
                acc[2][ci] += kv2 * xv;
                acc[3][ci] += kv3 * xv;
            }
        }
    }

    #pragma unroll
    for (int s = 0; s < 4; ++s) {
        int co = s * 64 + cq;
        #pragma unroll
        for (int s1 = 0; s1 < 2; ++s1) {
            float2 v = make_float2(acc[s][s1 * 2 + 0], acc[s][s1 * 2 + 1]);
            *(float2*)&out[(((size_t)b * 256 + co) * 128 + 2 * h + s1) * 128 + 2 * w] = v;
        }
    }
}

extern "C" void kernel_launch(void* const* d_in, const int* in_sizes, int n_in,
                              void* d_out, int out_size, void* d_ws, size_t ws_size,
                              hipStream_t stream) {
    const float* x  = (const float*)d_in[0];
    const float* w1 = (const float*)d_in[1];
    const float* b1 = (const float*)d_in[2];
    const float* w2 = (const float*)d_in[3];
    const float* b2 = (const float*)d_in[4];
    float* out = (float*)d_out;

    char* wsb = (char*)d_ws;
    bf16*  featb = (bf16*)wsb;                          // 2,097,152 B
    float* kern  = (float*)(wsb + 2097152);             // 6,553,600 B
    bf16*  w1b   = (bf16*)(wsb + 8650752);              // 294,912 B

    k0a_transform<<<dim3((W1B_ELEMS + 255) / 256), 256, 0, stream>>>(w1, w1b);
    k1_mfma<<<dim3(BB * HH), 256, 0, stream>>>(x, w1b, b1, featb);
    k2_kernelpred<<<dim3(BB * HH), 256, 0, stream>>>(featb, w2, b2, kern);
    k3_reassemble<<<dim3(16, BB * HH), 256, 0, stream>>>(x, kern, out);
}

// Round 3
// 168.741 us; speedup vs baseline: 1.8839x; 1.0816x over previous
//
#include <hip/hip_runtime.h>

// CARAFE on MI355X. B=4, C=256, H=W=64, CMID=64, NK=100 (s=2, k=5).
// k0a: w1 -> w1c bf16 [c8][kk][q][oc][8ic]  (exact per-chunk LDS image for k1)
// k1 : conv3x3+relu as bf16 MFMA implicit GEMM, 512 thr, async A-staging -> featb bf16 NHWC
// k2 : conv1x1 (64->100) + softmax -> kern fp32 [bh][k(25)][w(64)][s(4)] (k3-ready layout)
// k3 : reassembly + pixel shuffle, vectorized f32x4 LDS reads
// out[b, s*64 + c/4, 2h + (c%4)/2, 2w + (c%4)%2] = sum_k kern[b,s*25+k,h,w] * xpad[b,c,h+kh-2,w+kw-2]

#define BB 4
#define CC 256
#define HH 64
#define WW 64
#define CMID 64
#define NKCH 100

typedef __bf16 bf16;
typedef __bf16 bf16x8 __attribute__((ext_vector_type(8)));
typedef float f32x4 __attribute__((ext_vector_type(4)));

__device__ __forceinline__ void async_copy16(const void* gsrc, void* ldst) {
    __builtin_amdgcn_global_load_lds(
        (__attribute__((address_space(1))) void*)(void*)gsrc,
        (__attribute__((address_space(3))) void*)ldst, 16, 0, 0);
}

// ---------------- k0a: w1 [oc][ic][3][3] fp32 -> w1c bf16 [c8][kk][q][oc][8] ----------------
__global__ void k0a_transform(const float* __restrict__ w1, bf16* __restrict__ w1c) {
    int idx = blockIdx.x * 256 + threadIdx.x;
    if (idx >= 147456) return;
    int i8 = idx & 7;
    int oc = (idx >> 3) & 63;
    int q  = (idx >> 9) & 3;
    int t2 = idx >> 11;            // 0..71
    int kk = t2 % 9;
    int c8 = t2 / 9;
    int ic = c8 * 32 + q * 8 + i8;
    w1c[idx] = (bf16)w1[(oc * 256 + ic) * 9 + kk];
}

// ---------------- k1: conv3x3 (256->64) + relu via MFMA -> featb bf16 NHWC ----------------
// grid 256 (bh), 512 threads = 8 waves. Wave (mhalf=wid&1, nq=wid>>1): 32oc x 16px tile.
__global__ __launch_bounds__(512) void k1_mfma(const float* __restrict__ x,
        const bf16* __restrict__ w1c, const float* __restrict__ b1,
        bf16* __restrict__ featb) {
    int bh = blockIdx.x;
    int b = bh >> 6, h = bh & 63;
    int tid = threadIdx.x;
    int lane = tid & 63, wid = tid >> 6;
    int l15 = lane & 15, quad = lane >> 4;
    int mhalf = wid & 1, nq = wid >> 1;

    __shared__ __align__(16) bf16 xs[3 * 66 * 40];   // [r][slot0..65][ic32+pad8]; stride 80B
    __shared__ __align__(16) bf16 wlds[36 * 512];    // [kk*4+q][oc][8ic] = chunk image

    for (int i = tid; i < 3 * 66 * 40; i += 512) xs[i] = (bf16)0.f;
    __syncthreads();

    f32x4 acc0 = {0.f, 0.f, 0.f, 0.f}, acc1 = {0.f, 0.f, 0.f, 0.f};
    const float* xb = x + (size_t)b * (CC * HH * WW);

    for (int c8 = 0; c8 < 8; ++c8) {
        // A: 36 async 1KB copies, dst = uniform base + lane*16 (contiguous image)
        for (int t = wid; t < 36; t += 8)
            async_copy16(w1c + (((c8 * 36 + t) << 9) + lane * 8), (void*)&wlds[t << 9]);
        // B: lane-coalesced fp32 row reads, packed bf16-pair ds_writes
        int ic0 = c8 * 32;
        #pragma unroll
        for (int j = 0; j < 6; ++j) {
            int task = wid + j * 8;          // 48 tasks: (p=task&15, r=task>>4)
            int p = task & 15, r = task >> 4;
            int hr = h - 1 + r;
            if (hr >= 0 && hr < HH) {
                const float* src = xb + ((size_t)(ic0 + 2 * p) * (HH * WW)) + hr * WW + lane;
                float f0 = src[0], f1 = src[HH * WW];
                union { bf16 hh[2]; unsigned u; } cv;
                cv.hh[0] = (bf16)f0; cv.hh[1] = (bf16)f1;
                *(unsigned*)&xs[(r * 66 + 1 + lane) * 40 + 2 * p] = cv.u;
            }
        }
        __syncthreads();   // drains ds_write + global_load_lds
        #pragma unroll
        for (int kk = 0; kk < 9; ++kk) {
            int r3 = kk / 3, kw = kk % 3;
            bf16x8 a0 = *(const bf16x8*)&wlds[((kk * 4 + quad) * 64 + mhalf * 32 + l15) * 8];
            bf16x8 a1 = *(const bf16x8*)&wlds[((kk * 4 + quad) * 64 + mhalf * 32 + 16 + l15) * 8];
            bf16x8 bf = *(const bf16x8*)&xs[(r3 * 66 + nq * 16 + l15 + kw) * 40 + quad * 8];
            acc0 = __builtin_amdgcn_mfma_f32_16x16x32_bf16(a0, bf, acc0, 0, 0, 0);
            acc1 = __builtin_amdgcn_mfma_f32_16x16x32_bf16(a1, bf, acc1, 0, 0, 0);
        }
        __syncthreads();
    }

    // epilogue: D col(l15)=px, row(quad*4+reg)=oc (within 16x16 tile)
    int px = nq * 16 + l15;
    #pragma unroll
    for (int mi = 0; mi < 2; ++mi) {
        int oc0 = mhalf * 32 + mi * 16 + quad * 4;
        float4 bv = *(const float4*)&b1[oc0];
        f32x4 v = mi ? acc1 : acc0;
        union { bf16 hh[4]; uint2 u; } o;
        o.hh[0] = (bf16)fmaxf(v[0] + bv.x, 0.f);
        o.hh[1] = (bf16)fmaxf(v[1] + bv.y, 0.f);
        o.hh[2] = (bf16)fmaxf(v[2] + bv.z, 0.f);
        o.hh[3] = (bf16)fmaxf(v[3] + bv.w, 0.f);
        *(uint2*)&featb[((size_t)bh * 64 + px) * 64 + oc0] = o.u;
    }
}

// ---------------- k2: conv1x1 (64->100) + softmax -> kern [bh][k][w][s] ----------------
__global__ __launch_bounds__(256) void k2_kernelpred(const bf16* __restrict__ featb,
        const float* __restrict__ w2, const float* __restrict__ b2,
        float* __restrict__ kern) {
    int bh = blockIdx.x;
    int tid = threadIdx.x;
    int w = tid & 63;
    int s = tid >> 6;                 // softmax channel = s*25 + k

    __shared__ float fs[64 * 65];
    __shared__ __align__(16) float ws2[NKCH * 64];
    __shared__ float red[2][4][64];
    __shared__ __align__(16) float kts[25 * 64 * 4];   // [k][w][s]

    for (int i = tid; i < 64 * 64; i += 256) {
        int ic = i & 63;
        int ww = i >> 6;
        fs[ic * 65 + ww] = (float)featb[(size_t)bh * 4096 + i];
    }
    for (int i = tid; i < NKCH * 64; i += 256) ws2[i] = w2[i];
    __syncthreads();

    float4 fv[16];
    #pragma unroll
    for (int q = 0; q < 16; ++q) {
        fv[q].x = fs[(4 * q + 0) * 65 + w];
        fv[q].y = fs[(4 * q + 1) * 65 + w];
        fv[q].z = fs[(4 * q + 2) * 65 + w];
        fv[q].w = fs[(4 * q + 3) * 65 + w];
    }

    float lg[25];
    for (int i = 0; i < 25; ++i) {
        int oc = s * 25 + i;
        float a = b2[oc];
        const float4* wr = (const float4*)&ws2[oc * 64];   // wave-uniform broadcast
        #pragma unroll
        for (int q = 0; q < 16; ++q) {
            float4 wv = wr[q];
            a += fv[q].x * wv.x + fv[q].y * wv.y + fv[q].z * wv.z + fv[q].w * wv.w;
        }
        lg[i] = a;
    }

    float m = -1e30f;
    #pragma unroll
    for (int i = 0; i < 25; ++i) m = fmaxf(m, lg[i]);
    red[0][s][w] = m;
    __syncthreads();
    m = fmaxf(fmaxf(red[0][0][w], red[0][1][w]), fmaxf(red[0][2][w], red[0][3][w]));
    float ssum = 0.f;
    #pragma unroll
    for (int i = 0; i < 25; ++i) { lg[i] = __expf(lg[i] - m); ssum += lg[i]; }
    red[1][s][w] = ssum;
    __syncthreads();
    ssum = red[1][0][w] + red[1][1][w] + red[1][2][w] + red[1][3][w];
    float inv = 1.f / ssum;
    #pragma unroll
    for (int i = 0; i < 25; ++i) kts[(i * 64 + w) * 4 + s] = lg[i] * inv;
    __syncthreads();
    // coalesced float4 store of the transposed block
    float* kout = kern + (size_t)bh * 6400;
    for (int i = tid; i < 1600; i += 256)
        *(float4*)&kout[i * 4] = *(const float4*)&kts[i * 4];
}

// ---------------- k3: reassembly + pixel shuffle ----------------
// grid (16, 256): chunk of 16 channels x bh. 256 thr: w=tid&63, cg=tid>>6 -> 4 channels each.
__global__ __launch_bounds__(256) void k3_reassemble(const float* __restrict__ x,
        const float* __restrict__ kern, float* __restrict__ out) {
    int chunk = blockIdx.x;
    int bh = blockIdx.y;
    int b = bh >> 6, h = bh & 63;
    int tid = threadIdx.x;
    int w = tid & 63;
    int cg = tid >> 6;
    int wid = cg;

    __shared__ __align__(16) float kt[6400];          // [k][w][s4]
    __shared__ __align__(16) float xs[5 * 68 * 20];   // [r][slot0..67][cc16+pad4]; stride 80B

    // kt: pure async memcpy (layout = global layout)
    const float* ksrc = kern + (size_t)bh * 6400;
    for (int t = wid; t < 25; t += 4)
        async_copy16(ksrc + t * 256 + (tid & 63) * 4, (void*)&kt[t * 256]);

    // xs: lane-coalesced reads, stride-20 writes
    for (int i = tid; i < 16 * 5 * 64; i += 256) {
        int ww = i & 63;
        int rr = (i >> 6) % 5;
        int cc = i / 320;
        int hr = h - 2 + rr;
        float v = (hr >= 0 && hr < HH)
            ? x[(((size_t)b * CC + chunk * 16 + cc) * HH + hr) * WW + ww] : 0.f;
        xs[(rr * 68 + 2 + ww) * 20 + cc] = v;
    }
    for (int i = tid; i < 320; i += 256) {            // zero pad slots 0,1,66,67
        int cc = i & 15;
        int q = (i >> 4) & 3;
        int rr = i >> 6;
        int slot = (q < 2) ? q : (q + 64);
        xs[(rr * 68 + slot) * 20 + cc] = 0.f;
    }
    __syncthreads();

    f32x4 a0 = {0.f,0.f,0.f,0.f}, a1 = {0.f,0.f,0.f,0.f};
    f32x4 a2 = {0.f,0.f,0.f,0.f}, a3 = {0.f,0.f,0.f,0.f};
    int cg4 = cg * 4;
    #pragma unroll
    for (int r = 0; r < 5; ++r) {
        #pragma unroll
        for (int kw = 0; kw < 5; ++kw) {
            f32x4 kv = *(const f32x4*)&kt[((r * 5 + kw) * 64 + w) * 4];
            f32x4 xv = *(const f32x4*)&xs[(r * 68 + w + kw) * 20 + cg4];
            a0 += kv.x * xv;
            a1 += kv.y * xv;
            a2 += kv.z * xv;
            a3 += kv.w * xv;
        }
    }

    int cq = chunk * 4 + cg;
    f32x4 accs[4] = {a0, a1, a2, a3};
    #pragma unroll
    for (int s = 0; s < 4; ++s) {
        size_t base = (((size_t)b * 256 + s * 64 + cq) * 128 + 2 * h) * 128 + 2 * w;
        *(float2*)&out[base]       = make_float2(accs[s][0], accs[s][1]);
        *(float2*)&out[base + 128] = make_float2(accs[s][2], accs[s][3]);
    }
}

extern "C" void kernel_launch(void* const* d_in, const int* in_sizes, int n_in,
                              void* d_out, int out_size, void* d_ws, size_t ws_size,
                              hipStream_t stream) {
    const float* x  = (const float*)d_in[0];
    const float* w1 = (const float*)d_in[1];
    const float* b1 = (const float*)d_in[2];
    const float* w2 = (const float*)d_in[3];
    const float* b2 = (const float*)d_in[4];
    float* out = (float*)d_out;

    char* wsb = (char*)d_ws;
    bf16*  featb = (bf16*)wsb;                   // 2,097,152 B
    float* kern  = (float*)(wsb + 2097152);      // 6,553,600 B
    bf16*  w1c   = (bf16*)(wsb + 8650752);       // 294,912 B

    k0a_transform<<<dim3(576), 256, 0, stream>>>(w1, w1c);
    k1_mfma<<<dim3(BB * HH), 512, 0, stream>>>(x, w1c, b1, featb);
    k2_kernelpred<<<dim3(BB * HH), 256, 0, stream>>>(featb, w2, b2, kern);
    k3_reassemble<<<dim3(16, BB * HH), 256, 0, stream>>>(x, kern, out);
}